// Round 1
// baseline (433.346 us; speedup 1.0000x reference)
//
#include <hip/hip_runtime.h>
#include <math.h>

// Problem: x[16][13][512][768] f32 -> out[16][13][3*768]
//   out[..., 0:768]    = sum over seq
//   out[..., 768:1536] = std (ddof=1) over seq
//   out[..., 1536:2304]= max over seq
#define BATCH_LAYERS 208   // 16*13
#define SEQ 512
#define HID 768
#define COLS 192           // HID / 4 (float4 columns)
#define CHUNKS 4
#define ROWS (SEQ / CHUNKS) // 128

// ws layout: per partial-block (208*4 of them): [sum4 x192][sumsq4 x192][max4 x192]
// = 576 float4 per block -> total 832*576*16 B = 7.66 MB

__global__ __launch_bounds__(COLS) void msm_partial(
    const float* __restrict__ x, float4* __restrict__ ws)
{
    const int blk   = blockIdx.x;          // 0 .. 208*CHUNKS-1
    const int bl    = blk / CHUNKS;        // (b,l) pair
    const int chunk = blk % CHUNKS;
    const int col   = threadIdx.x;         // 0 .. 191

    const float4* p = (const float4*)(x + (size_t)bl * SEQ * HID
                                        + (size_t)chunk * ROWS * HID) + col;

    float sx = 0.f, sy = 0.f, sz = 0.f, sw = 0.f;
    float qx = 0.f, qy = 0.f, qz = 0.f, qw = 0.f;
    float mx = -INFINITY, my = -INFINITY, mz = -INFINITY, mw = -INFINITY;

    #pragma unroll 8
    for (int i = 0; i < ROWS; ++i) {
        float4 v = p[(size_t)i * COLS];
        sx += v.x; sy += v.y; sz += v.z; sw += v.w;
        qx = fmaf(v.x, v.x, qx); qy = fmaf(v.y, v.y, qy);
        qz = fmaf(v.z, v.z, qz); qw = fmaf(v.w, v.w, qw);
        mx = fmaxf(mx, v.x); my = fmaxf(my, v.y);
        mz = fmaxf(mz, v.z); mw = fmaxf(mw, v.w);
    }

    float4* o = ws + (size_t)blk * (3 * COLS) + col;
    o[0]        = make_float4(sx, sy, sz, sw);
    o[COLS]     = make_float4(qx, qy, qz, qw);
    o[2 * COLS] = make_float4(mx, my, mz, mw);
}

__global__ __launch_bounds__(COLS) void msm_combine(
    const float4* __restrict__ ws, float* __restrict__ out)
{
    const int bl  = blockIdx.x;   // 0..207
    const int col = threadIdx.x;  // 0..191

    float sx = 0.f, sy = 0.f, sz = 0.f, sw = 0.f;
    float qx = 0.f, qy = 0.f, qz = 0.f, qw = 0.f;
    float mx = -INFINITY, my = -INFINITY, mz = -INFINITY, mw = -INFINITY;

    #pragma unroll
    for (int c = 0; c < CHUNKS; ++c) {
        const float4* o = ws + (size_t)(bl * CHUNKS + c) * (3 * COLS) + col;
        float4 s = o[0], q = o[COLS], m = o[2 * COLS];
        sx += s.x; sy += s.y; sz += s.z; sw += s.w;
        qx += q.x; qy += q.y; qz += q.z; qw += q.w;
        mx = fmaxf(mx, m.x); my = fmaxf(my, m.y);
        mz = fmaxf(mz, m.z); mw = fmaxf(mw, m.w);
    }

    const float n    = (float)SEQ;
    const float invn = 1.0f / n;
    const float invn1 = 1.0f / (n - 1.0f);

    float vx = fmaxf((qx - sx * sx * invn) * invn1, 0.f);
    float vy = fmaxf((qy - sy * sy * invn) * invn1, 0.f);
    float vz = fmaxf((qz - sz * sz * invn) * invn1, 0.f);
    float vw = fmaxf((qw - sw * sw * invn) * invn1, 0.f);

    float4* ob = (float4*)(out + (size_t)bl * 3 * HID);
    ob[col]            = make_float4(sx, sy, sz, sw);
    ob[COLS + col]     = make_float4(sqrtf(vx), sqrtf(vy), sqrtf(vz), sqrtf(vw));
    ob[2 * COLS + col] = make_float4(mx, my, mz, mw);
}

extern "C" void kernel_launch(void* const* d_in, const int* in_sizes, int n_in,
                              void* d_out, int out_size, void* d_ws, size_t ws_size,
                              hipStream_t stream) {
    const float* x = (const float*)d_in[0];
    float* out = (float*)d_out;
    float4* ws = (float4*)d_ws;

    msm_partial<<<BATCH_LAYERS * CHUNKS, COLS, 0, stream>>>(x, ws);
    msm_combine<<<BATCH_LAYERS, COLS, 0, stream>>>(ws, out);
}

// Round 3
// 394.505 us; speedup vs baseline: 1.0985x; 1.0985x over previous
//
#include <hip/hip_runtime.h>
#include <math.h>

// x[16][13][512][768] f32 -> out[16][13][3*768]
//   out[..., 0:768]    = sum over seq
//   out[..., 768:1536] = std (ddof=1) over seq
//   out[..., 1536:2304]= max over seq
//
// Single fused kernel: 208 blocks (one per (batch,layer) pair), 768 threads =
// 4 row-groups x 192 float4-columns. Each group streams 128 rows coalesced
// (1 KB/wave/instr, nontemporal - data is single-use), partials combined
// through LDS. No workspace round-trip, one launch.
#define BL   208            // 16*13
#define SEQ  512
#define HID  768
#define COLS 192            // HID/4 float4 columns
#define GROUPS 4
#define ROWS (SEQ / GROUPS) // 128 rows per group
#define TPB  (COLS * GROUPS) // 768 threads, 12 waves

typedef float f4v __attribute__((ext_vector_type(4)));

__global__ __launch_bounds__(TPB) void msm_fused(
    const float* __restrict__ x, float* __restrict__ out)
{
    // partials from groups 1..3: [stat][group-1][col]
    __shared__ f4v sh[3][GROUPS - 1][COLS];

    const int bl  = blockIdx.x;
    const int tid = threadIdx.x;
    const int grp = tid / COLS;   // 0..3
    const int col = tid % COLS;   // 0..191

    const f4v* p = (const f4v*)(x + (size_t)bl * SEQ * HID
                                  + (size_t)grp * ROWS * HID) + col;

    float sx = 0.f, sy = 0.f, sz = 0.f, sw = 0.f;
    float qx = 0.f, qy = 0.f, qz = 0.f, qw = 0.f;
    float mx = -INFINITY, my = -INFINITY, mz = -INFINITY, mw = -INFINITY;

    #pragma unroll 8
    for (int i = 0; i < ROWS; ++i) {
        f4v v = __builtin_nontemporal_load(p + (size_t)i * COLS);
        sx += v.x; sy += v.y; sz += v.z; sw += v.w;
        qx = fmaf(v.x, v.x, qx); qy = fmaf(v.y, v.y, qy);
        qz = fmaf(v.z, v.z, qz); qw = fmaf(v.w, v.w, qw);
        mx = fmaxf(mx, v.x); my = fmaxf(my, v.y);
        mz = fmaxf(mz, v.z); mw = fmaxf(mw, v.w);
    }

    if (grp > 0) {
        sh[0][grp - 1][col] = (f4v){sx, sy, sz, sw};
        sh[1][grp - 1][col] = (f4v){qx, qy, qz, qw};
        sh[2][grp - 1][col] = (f4v){mx, my, mz, mw};
    }
    __syncthreads();

    if (grp == 0) {
        #pragma unroll
        for (int g = 0; g < GROUPS - 1; ++g) {
            f4v s = sh[0][g][col];
            f4v q = sh[1][g][col];
            f4v m = sh[2][g][col];
            sx += s.x; sy += s.y; sz += s.z; sw += s.w;
            qx += q.x; qy += q.y; qz += q.z; qw += q.w;
            mx = fmaxf(mx, m.x); my = fmaxf(my, m.y);
            mz = fmaxf(mz, m.z); mw = fmaxf(mw, m.w);
        }

        const float invn  = 1.0f / (float)SEQ;
        const float invn1 = 1.0f / ((float)SEQ - 1.0f);

        float vx = fmaxf((qx - sx * sx * invn) * invn1, 0.f);
        float vy = fmaxf((qy - sy * sy * invn) * invn1, 0.f);
        float vz = fmaxf((qz - sz * sz * invn) * invn1, 0.f);
        float vw = fmaxf((qw - sw * sw * invn) * invn1, 0.f);

        f4v* ob = (f4v*)(out + (size_t)bl * 3 * HID);
        ob[col]            = (f4v){sx, sy, sz, sw};
        ob[COLS + col]     = (f4v){sqrtf(vx), sqrtf(vy), sqrtf(vz), sqrtf(vw)};
        ob[2 * COLS + col] = (f4v){mx, my, mz, mw};
    }
}

extern "C" void kernel_launch(void* const* d_in, const int* in_sizes, int n_in,
                              void* d_out, int out_size, void* d_ws, size_t ws_size,
                              hipStream_t stream) {
    const float* x = (const float*)d_in[0];
    float* out = (float*)d_out;
    msm_fused<<<BL, TPB, 0, stream>>>(x, out);
}